// Round 2
// baseline (809.406 us; speedup 1.0000x reference)
//
#include <hip/hip_runtime.h>
#include <hip/hip_bf16.h>

#define BN 16384
#define NPTS 8192
#define KNN 16

// ---------------- pack xyz -> float4(x,y,z,|x|^2) ----------------
__global__ __launch_bounds__(256) void pack_xyz(const float* __restrict__ xyz,
                                                float4* __restrict__ xyz4) {
    int i = blockIdx.x * 256 + threadIdx.x;
    if (i < BN) {
        float x = xyz[i * 3 + 0], y = xyz[i * 3 + 1], z = xyz[i * 3 + 2];
        xyz4[i] = make_float4(x, y, z, x * x + y * y + z * z);
    }
}

// ---------------- brute-force KNN, one block per query row ----------------
__global__ __launch_bounds__(256) void knn_kernel(const float4* __restrict__ xyz4,
                                                  int* __restrict__ knn_idx) {
    __shared__ float sd[256 * 17];
    __shared__ int   si[256 * 17];
    __shared__ unsigned long long wred[4];
    int row = blockIdx.x;
    int b = row >> 13, n = row & (NPTS - 1);
    const float4* base = xyz4 + b * NPTS;
    int tid = threadIdx.x;
    float4 p = base[n];

    float ld[16]; int li[16];
#pragma unroll
    for (int i = 0; i < 16; i++) { ld[i] = 3e38f; li[i] = 0; }
    float lmax = 3e38f; int lslot = 0;

    for (int j = tid; j < NPTS; j += 256) {
        float4 c = base[j];
        float dot = fmaf(p.x, c.x, fmaf(p.y, c.y, p.z * c.z));
        float d = p.w + c.w - 2.f * dot;
        if (d < lmax) {
#pragma unroll
            for (int i = 0; i < 16; i++) {
                bool w = (i == lslot);
                ld[i] = w ? d : ld[i];
                li[i] = w ? j : li[i];
            }
            lmax = ld[0]; lslot = 0;
#pragma unroll
            for (int i = 1; i < 16; i++) {
                if (ld[i] > lmax) { lmax = ld[i]; lslot = i; }
            }
        }
    }
#pragma unroll
    for (int i = 0; i < 16; i++) { sd[tid * 17 + i] = ld[i]; si[tid * 17 + i] = li[i]; }
    __syncthreads();

    for (int r = 0; r < 16; r++) {
        float mv = 3e38f; int ms = 0;
#pragma unroll
        for (int i = 0; i < 16; i++) {
            float v = sd[tid * 17 + i];
            if (v < mv) { mv = v; ms = i; }
        }
        unsigned int key = __float_as_uint(mv);
        key = (key & 0x80000000u) ? ~key : (key | 0x80000000u);
        unsigned long long pk = ((unsigned long long)key << 32) | (unsigned int)(tid * 17 + ms);
#pragma unroll
        for (int off = 32; off > 0; off >>= 1) {
            unsigned long long o = __shfl_down(pk, off, 64);
            pk = (o < pk) ? o : pk;
        }
        if ((tid & 63) == 0) wred[tid >> 6] = pk;
        __syncthreads();
        if (tid == 0) {
            unsigned long long m = wred[0];
            for (int w = 1; w < 4; w++) m = (wred[w] < m) ? wred[w] : m;
            int slot = (int)(m & 0xffffffffu);
            knn_idx[row * 16 + r] = si[slot];
            sd[slot] = 3e38f;
        }
        __syncthreads();
    }
}

// ---------------- Q/K/V projections ----------------
__global__ __launch_bounds__(256) void qkv_kernel(const float* __restrict__ feats,
                                                  const float* __restrict__ wq,
                                                  const float* __restrict__ wk,
                                                  const float* __restrict__ wv,
                                                  float* __restrict__ Q,
                                                  float* __restrict__ Kf,
                                                  float* __restrict__ Vf) {
    __shared__ float swq[4096], swk[4096], swv[4096], fr[256];
    int tid = threadIdx.x;
    for (int i = tid; i < 1024; i += 256) {
        ((float4*)swq)[i] = ((const float4*)wq)[i];
        ((float4*)swk)[i] = ((const float4*)wk)[i];
        ((float4*)swv)[i] = ((const float4*)wv)[i];
    }
    int row0 = blockIdx.x * 64;
    int c = tid & 63, rl = tid >> 6;
    for (int rg = 0; rg < 16; rg++) {
        __syncthreads();
        fr[tid] = feats[(row0 + rg * 4) * 64 + tid];
        __syncthreads();
        float aq = 0.f, ak = 0.f, av = 0.f;
        int fb = rl * 64;
        for (int kk = 0; kk < 64; kk++) {
            float f = fr[fb + kk];
            aq = fmaf(f, swq[kk * 64 + c], aq);
            ak = fmaf(f, swk[kk * 64 + c], ak);
            av = fmaf(f, swv[kk * 64 + c], av);
        }
        int row = row0 + rg * 4 + rl;
        Q[row * 64 + c] = aq;
        Kf[row * 64 + c] = ak;
        Vf[row * 64 + c] = av;
    }
}

// ---------------- fused attention per row ----------------
__global__ __launch_bounds__(256) void attn_kernel(
    const float4* __restrict__ xyz4, const int* __restrict__ knn_idx,
    const float* __restrict__ Q, const float* __restrict__ Kf, const float* __restrict__ Vf,
    const float* __restrict__ feats,
    const float* __restrict__ dw1, const float* __restrict__ db1,
    const float* __restrict__ dw2, const float* __restrict__ db2,
    const float* __restrict__ gw1, const float* __restrict__ gb1,
    const float* __restrict__ gw2, const float* __restrict__ gb2,
    float* __restrict__ res) {
    __shared__ float swd2[4096], swg1[4096], swg2[4096];
    __shared__ float hbuf[16 * 68], abuf[16 * 68], posbuf[16 * 68];
    __shared__ float sdw1[192], sdb1[64], sdb2[64], sgb1[64], sgb2[64], qn[64];
    __shared__ int sidx[16];
    int tid = threadIdx.x;
    int row = blockIdx.x;
    int b = row >> 13;

    for (int i = tid; i < 1024; i += 256) {
        ((float4*)swd2)[i] = ((const float4*)dw2)[i];
        ((float4*)swg1)[i] = ((const float4*)gw1)[i];
        ((float4*)swg2)[i] = ((const float4*)gw2)[i];
    }
    if (tid < 192) sdw1[tid] = dw1[tid];
    if (tid < 64) {
        sdb1[tid] = db1[tid]; sdb2[tid] = db2[tid];
        sgb1[tid] = gb1[tid]; sgb2[tid] = gb2[tid];
        qn[tid] = Q[row * 64 + tid];
    }
    if (tid < 16) sidx[tid] = knn_idx[row * 16 + tid];
    __syncthreads();

    int j = tid >> 4, t = tid & 15, c0 = t * 4;
    int gidx = b * NPTS + sidx[j];
    float4 p = xyz4[row];
    float4 nb = xyz4[gidx];
    float rx = p.x - nb.x, ry = p.y - nb.y, rz = p.z - nb.z;
#pragma unroll
    for (int cc = 0; cc < 4; cc++) {
        int c = c0 + cc;
        float h = sdb1[c] + rx * sdw1[c] + ry * sdw1[64 + c] + rz * sdw1[128 + c];
        hbuf[j * 68 + c] = fmaxf(h, 0.f);
    }
    __syncthreads();

    // pos = relu(rel@W1+b1) @ W2 + b2
    float a0 = sdb2[c0], a1 = sdb2[c0 + 1], a2 = sdb2[c0 + 2], a3 = sdb2[c0 + 3];
    for (int e = 0; e < 64; e++) {
        float hv = hbuf[j * 68 + e];
        float4 w = *(const float4*)&swd2[e * 64 + c0];
        a0 = fmaf(hv, w.x, a0); a1 = fmaf(hv, w.y, a1);
        a2 = fmaf(hv, w.z, a2); a3 = fmaf(hv, w.w, a3);
    }
    float4 kfv = *(const float4*)&Kf[gidx * 64 + c0];
    posbuf[j * 68 + c0] = a0; posbuf[j * 68 + c0 + 1] = a1;
    posbuf[j * 68 + c0 + 2] = a2; posbuf[j * 68 + c0 + 3] = a3;
    __syncthreads();
    // tvec = q - k + pos  (overwrite hbuf)
    hbuf[j * 68 + c0]     = qn[c0]     - kfv.x + a0;
    hbuf[j * 68 + c0 + 1] = qn[c0 + 1] - kfv.y + a1;
    hbuf[j * 68 + c0 + 2] = qn[c0 + 2] - kfv.z + a2;
    hbuf[j * 68 + c0 + 3] = qn[c0 + 3] - kfv.w + a3;
    __syncthreads();

    // h2 = relu(tvec @ gw1 + gb1)
    float h0 = sgb1[c0], h1 = sgb1[c0 + 1], h2 = sgb1[c0 + 2], h3 = sgb1[c0 + 3];
    for (int e = 0; e < 64; e++) {
        float tv = hbuf[j * 68 + e];
        float4 w = *(const float4*)&swg1[e * 64 + c0];
        h0 = fmaf(tv, w.x, h0); h1 = fmaf(tv, w.y, h1);
        h2 = fmaf(tv, w.z, h2); h3 = fmaf(tv, w.w, h3);
    }
    abuf[j * 68 + c0]     = fmaxf(h0, 0.f);
    abuf[j * 68 + c0 + 1] = fmaxf(h1, 0.f);
    abuf[j * 68 + c0 + 2] = fmaxf(h2, 0.f);
    abuf[j * 68 + c0 + 3] = fmaxf(h3, 0.f);
    __syncthreads();

    // attn = h2 @ gw2 + gb2  (write into hbuf)
    float g0 = sgb2[c0], g1 = sgb2[c0 + 1], g2 = sgb2[c0 + 2], g3 = sgb2[c0 + 3];
    for (int e = 0; e < 64; e++) {
        float av = abuf[j * 68 + e];
        float4 w = *(const float4*)&swg2[e * 64 + c0];
        g0 = fmaf(av, w.x, g0); g1 = fmaf(av, w.y, g1);
        g2 = fmaf(av, w.z, g2); g3 = fmaf(av, w.w, g3);
    }
    __syncthreads();
    hbuf[j * 68 + c0] = g0; hbuf[j * 68 + c0 + 1] = g1;
    hbuf[j * 68 + c0 + 2] = g2; hbuf[j * 68 + c0 + 3] = g3;
    __syncthreads();

    // softmax over 16 neighbors per channel, weighted sum of (V+pos)
    int g = tid >> 6, c = tid & 63;
    float m = -3e38f;
#pragma unroll
    for (int jj = 0; jj < 4; jj++) m = fmaxf(m, hbuf[(g * 4 + jj) * 68 + c]);
    abuf[tid] = m;
    __syncthreads();
    m = fmaxf(fmaxf(abuf[c], abuf[64 + c]), fmaxf(abuf[128 + c], abuf[192 + c]));
    float s = 0.f, pa = 0.f;
#pragma unroll
    for (int jj = 0; jj < 4; jj++) {
        int jn = g * 4 + jj;
        float a = hbuf[jn * 68 + c];
        float e = __expf(a - m);
        float v = Vf[(b * NPTS + sidx[jn]) * 64 + c];
        float po = posbuf[jn * 68 + c];
        s += e;
        pa = fmaf(e, v + po, pa);
    }
    __syncthreads();
    abuf[tid] = s;
    posbuf[tid] = pa;
    __syncthreads();
    if (tid < 64) {
        float st = abuf[c] + abuf[64 + c] + abuf[128 + c] + abuf[192 + c];
        float at = posbuf[c] + posbuf[64 + c] + posbuf[128 + c] + posbuf[192 + c];
        res[row * 64 + c] = at / st + feats[row * 64 + c];
    }
}

// ---------------- batchnorm reduce ----------------
__global__ __launch_bounds__(256) void reduce_kernel(const float* __restrict__ res,
                                                     float* __restrict__ accum) {
    __shared__ float sa[256], sq[256];
    int tid = threadIdx.x;
    const float* basep = res + blockIdx.x * 4096;
    float s = 0.f, q = 0.f;
#pragma unroll
    for (int i = 0; i < 16; i++) {
        float v = basep[i * 256 + tid];
        s += v;
        q = fmaf(v, v, q);
    }
    sa[tid] = s; sq[tid] = q;
    __syncthreads();
    if (tid < 64) {
        float ss = sa[tid] + sa[tid + 64] + sa[tid + 128] + sa[tid + 192];
        float qq = sq[tid] + sq[tid + 64] + sq[tid + 128] + sq[tid + 192];
        atomicAdd(&accum[tid], ss);
        atomicAdd(&accum[64 + tid], qq);
    }
}

// ---------------- batchnorm apply + fp32 output ----------------
__global__ __launch_bounds__(256) void norm_kernel(const float* __restrict__ res,
                                                   const float* __restrict__ accum,
                                                   const float* __restrict__ bng,
                                                   const float* __restrict__ bnb,
                                                   float* __restrict__ out) {
    int i = blockIdx.x * 256 + threadIdx.x;
    int c = i & 63;
    float mean = accum[c] * (1.f / 16384.f);
    float var = accum[64 + c] * (1.f / 16384.f) - mean * mean;
    float sc = rsqrtf(var + 1e-5f) * bng[c];
    out[i] = fmaf(res[i] - mean, sc, bnb[c]);
}

extern "C" void kernel_launch(void* const* d_in, const int* in_sizes, int n_in,
                              void* d_out, int out_size, void* d_ws, size_t ws_size,
                              hipStream_t stream) {
    const float* xyz  = (const float*)d_in[0];
    const float* feats = (const float*)d_in[1];
    const float* w_qs = (const float*)d_in[2];
    const float* w_ks = (const float*)d_in[3];
    const float* w_vs = (const float*)d_in[4];
    const float* dw1 = (const float*)d_in[5];
    const float* db1 = (const float*)d_in[6];
    const float* dw2 = (const float*)d_in[7];
    const float* db2 = (const float*)d_in[8];
    const float* gw1 = (const float*)d_in[9];
    const float* gb1 = (const float*)d_in[10];
    const float* gw2 = (const float*)d_in[11];
    const float* gb2 = (const float*)d_in[12];
    const float* bng = (const float*)d_in[13];
    const float* bnb = (const float*)d_in[14];

    char* ws = (char*)d_ws;
    float4* xyz4 = (float4*)ws;                       // 256 KB
    int* knn    = (int*)(ws + 262144);                // 1 MB
    float* Q    = (float*)(ws + 1310720);             // 4 MB
    float* Kf   = (float*)(ws + 5505024);             // 4 MB
    float* Vf   = (float*)(ws + 9699328);             // 4 MB
    float* res  = (float*)(ws + 13893632);            // 4 MB
    float* accum = (float*)(ws + 18087936);           // 512 B

    hipMemsetAsync(accum, 0, 512, stream);
    pack_xyz<<<64, 256, 0, stream>>>(xyz, xyz4);
    knn_kernel<<<16384, 256, 0, stream>>>(xyz4, knn);
    qkv_kernel<<<256, 256, 0, stream>>>(feats, w_qs, w_ks, w_vs, Q, Kf, Vf);
    attn_kernel<<<16384, 256, 0, stream>>>(xyz4, knn, Q, Kf, Vf, feats,
                                           dw1, db1, dw2, db2, gw1, gb1, gw2, gb2, res);
    reduce_kernel<<<256, 256, 0, stream>>>(res, accum);
    norm_kernel<<<4096, 256, 0, stream>>>(res, accum, bng, bnb, (float*)d_out);
}

// Round 3
// 448.211 us; speedup vs baseline: 1.8059x; 1.8059x over previous
//
#include <hip/hip_runtime.h>
#include <hip/hip_bf16.h>

#define BN 16384
#define NPTS 8192
#define KNN 16

// ---------------- pack xyz -> float4(x,y,z,|x|^2) ----------------
__global__ __launch_bounds__(256) void pack_xyz(const float* __restrict__ xyz,
                                                float4* __restrict__ xyz4) {
    int i = blockIdx.x * 256 + threadIdx.x;
    if (i < BN) {
        float x = xyz[i * 3 + 0], y = xyz[i * 3 + 1], z = xyz[i * 3 + 2];
        xyz4[i] = make_float4(x, y, z, x * x + y * y + z * z);
    }
}

// ---------------- KNN via threshold rank-selection ----------------
// One block per query row. Distances live in registers; binary-search a
// threshold T with 16 <= count(d<T) <= 128, compact survivors to LDS,
// exact rank with index tie-break (== jax.lax.top_k stable semantics).
__global__ __launch_bounds__(256) void knn_kernel(const float4* __restrict__ xyz4,
                                                  int* __restrict__ knn_idx) {
    __shared__ float sred[4];
    __shared__ int scnt[4];
    __shared__ float ck[256];
    __shared__ int ci[256];
    __shared__ int scounter;
    int row = blockIdx.x;
    int b = row >> 13, n = row & (NPTS - 1);
    const float4* base = xyz4 + b * NPTS;
    int tid = threadIdx.x;
    int lane = tid & 63, wid = tid >> 6;
    float4 p = base[n];

    float dreg[32];
    float lmin = 1e30f;
#pragma unroll
    for (int i = 0; i < 32; i++) {
        int j = tid + (i << 8);
        float4 c = base[j];
        float dot = fmaf(p.x, c.x, fmaf(p.y, c.y, p.z * c.z));
        float d = p.w + c.w - 2.f * dot;
        dreg[i] = d;
        lmin = fminf(lmin, d);
    }

    // hi seed: max over threads of per-thread min -> count(d<hi) >= 255
    float wmax = lmin;
#pragma unroll
    for (int off = 32; off; off >>= 1) wmax = fmaxf(wmax, __shfl_xor(wmax, off, 64));
    if (lane == 0) sred[wid] = wmax;
    if (tid == 0) scounter = 0;
    __syncthreads();
    float hi = fmaxf(fmaxf(sred[0], sred[1]), fmaxf(sred[2], sred[3])) * 1.0001f + 1e-6f;
    float lo = 0.f;   // count(d<0) <= 1 (self distance may round slightly negative)
    float T = hi;

    for (int iter = 0; iter < 24; iter++) {
        float mid = 0.5f * (lo + hi);
        int cnt = 0;
#pragma unroll
        for (int i = 0; i < 32; i++) cnt += (dreg[i] < mid) ? 1 : 0;
#pragma unroll
        for (int off = 32; off; off >>= 1) cnt += __shfl_xor(cnt, off, 64);
        __syncthreads();               // protect scnt reuse across iterations
        if (lane == 0) scnt[wid] = cnt;
        __syncthreads();
        int total = scnt[0] + scnt[1] + scnt[2] + scnt[3];
        if (total >= 16 && total <= 128) { T = mid; break; }
        if (total < 16) lo = mid; else hi = mid;
        T = hi;                        // invariant: count(d<hi) >= 16
    }
    __syncthreads();

    // compact survivors
#pragma unroll
    for (int i = 0; i < 32; i++) {
        if (dreg[i] < T) {
            int pos = atomicAdd(&scounter, 1);
            if (pos < 256) { ck[pos] = dreg[i]; ci[pos] = tid + (i << 8); }
        }
    }
    __syncthreads();
    int cc = min(scounter, 256);

    // exact rank among survivors (strict total order: dist, then index)
    if (tid < cc) {
        float myk = ck[tid]; int myi = ci[tid];
        int rank = 0;
        for (int j2 = 0; j2 < cc; j2++) {
            float kj = ck[j2]; int ij = ci[j2];
            rank += (kj < myk || (kj == myk && ij < myi)) ? 1 : 0;
        }
        if (rank < 16) knn_idx[row * 16 + rank] = myi;
    }
}

// ---------------- Q/K/V projections ----------------
__global__ __launch_bounds__(256) void qkv_kernel(const float* __restrict__ feats,
                                                  const float* __restrict__ wq,
                                                  const float* __restrict__ wk,
                                                  const float* __restrict__ wv,
                                                  float* __restrict__ Q,
                                                  float* __restrict__ Kf,
                                                  float* __restrict__ Vf) {
    __shared__ float swq[4096], swk[4096], swv[4096], fr[256];
    int tid = threadIdx.x;
    for (int i = tid; i < 1024; i += 256) {
        ((float4*)swq)[i] = ((const float4*)wq)[i];
        ((float4*)swk)[i] = ((const float4*)wk)[i];
        ((float4*)swv)[i] = ((const float4*)wv)[i];
    }
    int row0 = blockIdx.x * 64;
    int c = tid & 63, rl = tid >> 6;
    for (int rg = 0; rg < 16; rg++) {
        __syncthreads();
        fr[tid] = feats[(row0 + rg * 4) * 64 + tid];
        __syncthreads();
        float aq = 0.f, ak = 0.f, av = 0.f;
        int fb = rl * 64;
        for (int kk = 0; kk < 64; kk++) {
            float f = fr[fb + kk];
            aq = fmaf(f, swq[kk * 64 + c], aq);
            ak = fmaf(f, swk[kk * 64 + c], ak);
            av = fmaf(f, swv[kk * 64 + c], av);
        }
        int row = row0 + rg * 4 + rl;
        Q[row * 64 + c] = aq;
        Kf[row * 64 + c] = ak;
        Vf[row * 64 + c] = av;
    }
}

// ---------------- fused attention per row ----------------
__global__ __launch_bounds__(256) void attn_kernel(
    const float4* __restrict__ xyz4, const int* __restrict__ knn_idx,
    const float* __restrict__ Q, const float* __restrict__ Kf, const float* __restrict__ Vf,
    const float* __restrict__ feats,
    const float* __restrict__ dw1, const float* __restrict__ db1,
    const float* __restrict__ dw2, const float* __restrict__ db2,
    const float* __restrict__ gw1, const float* __restrict__ gb1,
    const float* __restrict__ gw2, const float* __restrict__ gb2,
    float* __restrict__ res) {
    __shared__ float swd2[4096], swg1[4096], swg2[4096];
    __shared__ float hbuf[16 * 68], abuf[16 * 68], posbuf[16 * 68];
    __shared__ float sdw1[192], sdb1[64], sdb2[64], sgb1[64], sgb2[64], qn[64];
    __shared__ int sidx[16];
    int tid = threadIdx.x;
    int row = blockIdx.x;
    int b = row >> 13;

    for (int i = tid; i < 1024; i += 256) {
        ((float4*)swd2)[i] = ((const float4*)dw2)[i];
        ((float4*)swg1)[i] = ((const float4*)gw1)[i];
        ((float4*)swg2)[i] = ((const float4*)gw2)[i];
    }
    if (tid < 192) sdw1[tid] = dw1[tid];
    if (tid < 64) {
        sdb1[tid] = db1[tid]; sdb2[tid] = db2[tid];
        sgb1[tid] = gb1[tid]; sgb2[tid] = gb2[tid];
        qn[tid] = Q[row * 64 + tid];
    }
    if (tid < 16) sidx[tid] = knn_idx[row * 16 + tid];
    __syncthreads();

    int j = tid >> 4, t = tid & 15, c0 = t * 4;
    int gidx = b * NPTS + sidx[j];
    float4 p = xyz4[row];
    float4 nb = xyz4[gidx];
    float rx = p.x - nb.x, ry = p.y - nb.y, rz = p.z - nb.z;
#pragma unroll
    for (int cc = 0; cc < 4; cc++) {
        int c = c0 + cc;
        float h = sdb1[c] + rx * sdw1[c] + ry * sdw1[64 + c] + rz * sdw1[128 + c];
        hbuf[j * 68 + c] = fmaxf(h, 0.f);
    }
    __syncthreads();

    // pos = relu(rel@W1+b1) @ W2 + b2
    float a0 = sdb2[c0], a1 = sdb2[c0 + 1], a2 = sdb2[c0 + 2], a3 = sdb2[c0 + 3];
    for (int e = 0; e < 64; e++) {
        float hv = hbuf[j * 68 + e];
        float4 w = *(const float4*)&swd2[e * 64 + c0];
        a0 = fmaf(hv, w.x, a0); a1 = fmaf(hv, w.y, a1);
        a2 = fmaf(hv, w.z, a2); a3 = fmaf(hv, w.w, a3);
    }
    float4 kfv = *(const float4*)&Kf[gidx * 64 + c0];
    posbuf[j * 68 + c0] = a0; posbuf[j * 68 + c0 + 1] = a1;
    posbuf[j * 68 + c0 + 2] = a2; posbuf[j * 68 + c0 + 3] = a3;
    __syncthreads();
    // tvec = q - k + pos  (overwrite hbuf)
    hbuf[j * 68 + c0]     = qn[c0]     - kfv.x + a0;
    hbuf[j * 68 + c0 + 1] = qn[c0 + 1] - kfv.y + a1;
    hbuf[j * 68 + c0 + 2] = qn[c0 + 2] - kfv.z + a2;
    hbuf[j * 68 + c0 + 3] = qn[c0 + 3] - kfv.w + a3;
    __syncthreads();

    // h2 = relu(tvec @ gw1 + gb1)
    float h0 = sgb1[c0], h1 = sgb1[c0 + 1], h2 = sgb1[c0 + 2], h3 = sgb1[c0 + 3];
    for (int e = 0; e < 64; e++) {
        float tv = hbuf[j * 68 + e];
        float4 w = *(const float4*)&swg1[e * 64 + c0];
        h0 = fmaf(tv, w.x, h0); h1 = fmaf(tv, w.y, h1);
        h2 = fmaf(tv, w.z, h2); h3 = fmaf(tv, w.w, h3);
    }
    abuf[j * 68 + c0]     = fmaxf(h0, 0.f);
    abuf[j * 68 + c0 + 1] = fmaxf(h1, 0.f);
    abuf[j * 68 + c0 + 2] = fmaxf(h2, 0.f);
    abuf[j * 68 + c0 + 3] = fmaxf(h3, 0.f);
    __syncthreads();

    // attn = h2 @ gw2 + gb2  (write into hbuf)
    float g0 = sgb2[c0], g1 = sgb2[c0 + 1], g2 = sgb2[c0 + 2], g3 = sgb2[c0 + 3];
    for (int e = 0; e < 64; e++) {
        float av = abuf[j * 68 + e];
        float4 w = *(const float4*)&swg2[e * 64 + c0];
        g0 = fmaf(av, w.x, g0); g1 = fmaf(av, w.y, g1);
        g2 = fmaf(av, w.z, g2); g3 = fmaf(av, w.w, g3);
    }
    __syncthreads();
    hbuf[j * 68 + c0] = g0; hbuf[j * 68 + c0 + 1] = g1;
    hbuf[j * 68 + c0 + 2] = g2; hbuf[j * 68 + c0 + 3] = g3;
    __syncthreads();

    // softmax over 16 neighbors per channel, weighted sum of (V+pos)
    int g = tid >> 6, c = tid & 63;
    float m = -3e38f;
#pragma unroll
    for (int jj = 0; jj < 4; jj++) m = fmaxf(m, hbuf[(g * 4 + jj) * 68 + c]);
    abuf[tid] = m;
    __syncthreads();
    m = fmaxf(fmaxf(abuf[c], abuf[64 + c]), fmaxf(abuf[128 + c], abuf[192 + c]));
    float s = 0.f, pa = 0.f;
#pragma unroll
    for (int jj = 0; jj < 4; jj++) {
        int jn = g * 4 + jj;
        float a = hbuf[jn * 68 + c];
        float e = __expf(a - m);
        float v = Vf[(b * NPTS + sidx[jn]) * 64 + c];
        float po = posbuf[jn * 68 + c];
        s += e;
        pa = fmaf(e, v + po, pa);
    }
    __syncthreads();
    abuf[tid] = s;
    posbuf[tid] = pa;
    __syncthreads();
    if (tid < 64) {
        float st = abuf[c] + abuf[64 + c] + abuf[128 + c] + abuf[192 + c];
        float at = posbuf[c] + posbuf[64 + c] + posbuf[128 + c] + posbuf[192 + c];
        res[row * 64 + c] = at / st + feats[row * 64 + c];
    }
}

// ---------------- batchnorm reduce ----------------
__global__ __launch_bounds__(256) void reduce_kernel(const float* __restrict__ res,
                                                     float* __restrict__ accum) {
    __shared__ float sa[256], sq[256];
    int tid = threadIdx.x;
    const float* basep = res + blockIdx.x * 4096;
    float s = 0.f, q = 0.f;
#pragma unroll
    for (int i = 0; i < 16; i++) {
        float v = basep[i * 256 + tid];
        s += v;
        q = fmaf(v, v, q);
    }
    sa[tid] = s; sq[tid] = q;
    __syncthreads();
    if (tid < 64) {
        float ss = sa[tid] + sa[tid + 64] + sa[tid + 128] + sa[tid + 192];
        float qq = sq[tid] + sq[tid + 64] + sq[tid + 128] + sq[tid + 192];
        atomicAdd(&accum[tid], ss);
        atomicAdd(&accum[64 + tid], qq);
    }
}

// ---------------- batchnorm apply + fp32 output ----------------
__global__ __launch_bounds__(256) void norm_kernel(const float* __restrict__ res,
                                                   const float* __restrict__ accum,
                                                   const float* __restrict__ bng,
                                                   const float* __restrict__ bnb,
                                                   float* __restrict__ out) {
    int i = blockIdx.x * 256 + threadIdx.x;
    int c = i & 63;
    float mean = accum[c] * (1.f / 16384.f);
    float var = accum[64 + c] * (1.f / 16384.f) - mean * mean;
    float sc = rsqrtf(var + 1e-5f) * bng[c];
    out[i] = fmaf(res[i] - mean, sc, bnb[c]);
}

extern "C" void kernel_launch(void* const* d_in, const int* in_sizes, int n_in,
                              void* d_out, int out_size, void* d_ws, size_t ws_size,
                              hipStream_t stream) {
    const float* xyz  = (const float*)d_in[0];
    const float* feats = (const float*)d_in[1];
    const float* w_qs = (const float*)d_in[2];
    const float* w_ks = (const float*)d_in[3];
    const float* w_vs = (const float*)d_in[4];
    const float* dw1 = (const float*)d_in[5];
    const float* db1 = (const float*)d_in[6];
    const float* dw2 = (const float*)d_in[7];
    const float* db2 = (const float*)d_in[8];
    const float* gw1 = (const float*)d_in[9];
    const float* gb1 = (const float*)d_in[10];
    const float* gw2 = (const float*)d_in[11];
    const float* gb2 = (const float*)d_in[12];
    const float* bng = (const float*)d_in[13];
    const float* bnb = (const float*)d_in[14];

    char* ws = (char*)d_ws;
    float4* xyz4 = (float4*)ws;                       // 256 KB
    int* knn    = (int*)(ws + 262144);                // 1 MB
    float* Q    = (float*)(ws + 1310720);             // 4 MB
    float* Kf   = (float*)(ws + 5505024);             // 4 MB
    float* Vf   = (float*)(ws + 9699328);             // 4 MB
    float* res  = (float*)(ws + 13893632);            // 4 MB
    float* accum = (float*)(ws + 18087936);           // 512 B

    hipMemsetAsync(accum, 0, 512, stream);
    pack_xyz<<<64, 256, 0, stream>>>(xyz, xyz4);
    knn_kernel<<<16384, 256, 0, stream>>>(xyz4, knn);
    qkv_kernel<<<256, 256, 0, stream>>>(feats, w_qs, w_ks, w_vs, Q, Kf, Vf);
    attn_kernel<<<16384, 256, 0, stream>>>(xyz4, knn, Q, Kf, Vf, feats,
                                           dw1, db1, dw2, db2, gw1, gb1, gw2, gb2, res);
    reduce_kernel<<<256, 256, 0, stream>>>(res, accum);
    norm_kernel<<<4096, 256, 0, stream>>>(res, accum, bng, bnb, (float*)d_out);
}

// Round 4
// 283.953 us; speedup vs baseline: 2.8505x; 1.5785x over previous
//
#include <hip/hip_runtime.h>
#include <hip/hip_bf16.h>

#define BN 16384
#define NPTS 8192
#define KNN 16

typedef __attribute__((ext_vector_type(8))) short bf16x8;
typedef __attribute__((ext_vector_type(4))) float f32x4;
typedef __attribute__((ext_vector_type(4))) unsigned short u16x4;

static __device__ __forceinline__ unsigned short f2bf(float f) {
    union { float f; unsigned u; } v; v.f = f;
    unsigned r = v.u + 0x7fffu + ((v.u >> 16) & 1u);
    return (unsigned short)(r >> 16);
}

// ---------------- pack xyz -> float4(x,y,z,|x|^2) ----------------
__global__ __launch_bounds__(256) void pack_xyz(const float* __restrict__ xyz,
                                                float4* __restrict__ xyz4) {
    int i = blockIdx.x * 256 + threadIdx.x;
    if (i < BN) {
        float x = xyz[i * 3 + 0], y = xyz[i * 3 + 1], z = xyz[i * 3 + 2];
        xyz4[i] = make_float4(x, y, z, x * x + y * y + z * z);
    }
}

// ---------------- KNN via threshold rank-selection (unchanged) ----------------
__global__ __launch_bounds__(256) void knn_kernel(const float4* __restrict__ xyz4,
                                                  int* __restrict__ knn_idx) {
    __shared__ float sred[4];
    __shared__ int scnt[4];
    __shared__ float ck[256];
    __shared__ int ci[256];
    __shared__ int scounter;
    int row = blockIdx.x;
    int b = row >> 13, n = row & (NPTS - 1);
    const float4* base = xyz4 + b * NPTS;
    int tid = threadIdx.x;
    int lane = tid & 63, wid = tid >> 6;
    float4 p = base[n];

    float dreg[32];
    float lmin = 1e30f;
#pragma unroll
    for (int i = 0; i < 32; i++) {
        int j = tid + (i << 8);
        float4 c = base[j];
        float dot = fmaf(p.x, c.x, fmaf(p.y, c.y, p.z * c.z));
        float d = p.w + c.w - 2.f * dot;
        dreg[i] = d;
        lmin = fminf(lmin, d);
    }

    float wmax = lmin;
#pragma unroll
    for (int off = 32; off; off >>= 1) wmax = fmaxf(wmax, __shfl_xor(wmax, off, 64));
    if (lane == 0) sred[wid] = wmax;
    if (tid == 0) scounter = 0;
    __syncthreads();
    float hi = fmaxf(fmaxf(sred[0], sred[1]), fmaxf(sred[2], sred[3])) * 1.0001f + 1e-6f;
    float lo = 0.f;
    float T = hi;

    for (int iter = 0; iter < 24; iter++) {
        float mid = 0.5f * (lo + hi);
        int cnt = 0;
#pragma unroll
        for (int i = 0; i < 32; i++) cnt += (dreg[i] < mid) ? 1 : 0;
#pragma unroll
        for (int off = 32; off; off >>= 1) cnt += __shfl_xor(cnt, off, 64);
        __syncthreads();
        if (lane == 0) scnt[wid] = cnt;
        __syncthreads();
        int total = scnt[0] + scnt[1] + scnt[2] + scnt[3];
        if (total >= 16 && total <= 128) { T = mid; break; }
        if (total < 16) lo = mid; else hi = mid;
        T = hi;
    }
    __syncthreads();

#pragma unroll
    for (int i = 0; i < 32; i++) {
        if (dreg[i] < T) {
            int pos = atomicAdd(&scounter, 1);
            if (pos < 256) { ck[pos] = dreg[i]; ci[pos] = tid + (i << 8); }
        }
    }
    __syncthreads();
    int cc = min(scounter, 256);

    if (tid < cc) {
        float myk = ck[tid]; int myi = ci[tid];
        int rank = 0;
        for (int j2 = 0; j2 < cc; j2++) {
            float kj = ck[j2]; int ij = ci[j2];
            rank += (kj < myk || (kj == myk && ij < myi)) ? 1 : 0;
        }
        if (rank < 16) knn_idx[row * 16 + rank] = myi;
    }
}

// ---------------- Q/K/V projections (unchanged) ----------------
__global__ __launch_bounds__(256) void qkv_kernel(const float* __restrict__ feats,
                                                  const float* __restrict__ wq,
                                                  const float* __restrict__ wk,
                                                  const float* __restrict__ wv,
                                                  float* __restrict__ Q,
                                                  float* __restrict__ Kf,
                                                  float* __restrict__ Vf) {
    __shared__ float swq[4096], swk[4096], swv[4096], fr[256];
    int tid = threadIdx.x;
    for (int i = tid; i < 1024; i += 256) {
        ((float4*)swq)[i] = ((const float4*)wq)[i];
        ((float4*)swk)[i] = ((const float4*)wk)[i];
        ((float4*)swv)[i] = ((const float4*)wv)[i];
    }
    int row0 = blockIdx.x * 64;
    int c = tid & 63, rl = tid >> 6;
    for (int rg = 0; rg < 16; rg++) {
        __syncthreads();
        fr[tid] = feats[(row0 + rg * 4) * 64 + tid];
        __syncthreads();
        float aq = 0.f, ak = 0.f, av = 0.f;
        int fb = rl * 64;
        for (int kk = 0; kk < 64; kk++) {
            float f = fr[fb + kk];
            aq = fmaf(f, swq[kk * 64 + c], aq);
            ak = fmaf(f, swk[kk * 64 + c], ak);
            av = fmaf(f, swv[kk * 64 + c], av);
        }
        int row = row0 + rg * 4 + rl;
        Q[row * 64 + c] = aq;
        Kf[row * 64 + c] = ak;
        Vf[row * 64 + c] = av;
    }
}

// ---------------- fused attention, MFMA, 16 rows/block ----------------
// Wave-private m-rows: one barrier total. pos kept in C-frag registers.
// gamma_b2 omitted: constant over neighbors => cancels exactly in softmax.
__global__ __launch_bounds__(256, 2) void attn_mfma(
    const float4* __restrict__ xyz4, const int* __restrict__ knn_idx,
    const float* __restrict__ Q, const float* __restrict__ Kf, const float* __restrict__ Vf,
    const float* __restrict__ feats,
    const float* __restrict__ dw1, const float* __restrict__ db1,
    const float* __restrict__ dw2, const float* __restrict__ db2,
    const float* __restrict__ gw1, const float* __restrict__ gb1,
    const float* __restrict__ gw2,
    float* __restrict__ res) {
    // B-operand weights transposed: sW[n][k], stride 68 (b64 frag reads)
    __shared__ __align__(16) unsigned short sWd2[64 * 68];
    __shared__ __align__(16) unsigned short sWg1[64 * 68];
    __shared__ __align__(16) unsigned short sWg2[64 * 68];
    // A-operand activations [m][k], stride 72 (16B-aligned b128 frag reads)
    __shared__ __align__(16) unsigned short sA[256 * 72];
    __shared__ int sidx[256];
    __shared__ float sdw1[256];   // rows 0..2 = dw1, row 3 = db1

    int tid = threadIdx.x;
    int w = tid >> 6, lane = tid & 63, quad = lane >> 4, col = lane & 15;
    int r0 = blockIdx.x * 16;

    for (int i = tid; i < 4096; i += 256) {
        int e = i >> 6, c = i & 63;
        sWd2[c * 68 + e] = f2bf(dw2[i]);
        sWg1[c * 68 + e] = f2bf(gw1[i]);
        sWg2[c * 68 + e] = f2bf(gw2[i]);
    }
    if (tid < 192) sdw1[tid] = dw1[tid];
    else sdw1[tid] = db1[tid - 192];
    {
        int brow = r0 + (tid >> 4);
        int b = brow >> 13;
        sidx[tid] = b * NPTS + knn_idx[brow * 16 + (tid & 15)];
    }
    __syncthreads();   // the only barrier

    // ---- H1 = relu(rel @ dw1 + db1), thread per m-row, bf16 into sA ----
    {
        int m = tid;
        int brow = r0 + (m >> 4);
        float4 p = xyz4[brow];
        float4 nb = xyz4[sidx[m]];
        float rx = p.x - nb.x, ry = p.y - nb.y, rz = p.z - nb.z;
        for (int c0 = 0; c0 < 64; c0 += 8) {
            bf16x8 v;
#pragma unroll
            for (int cc = 0; cc < 8; cc++) {
                int c = c0 + cc;
                float h = sdw1[192 + c] + rx * sdw1[c] + ry * sdw1[64 + c] + rz * sdw1[128 + c];
                v[cc] = (short)f2bf(fmaxf(h, 0.f));
            }
            *(bf16x8*)&sA[m * 72 + c0] = v;
        }
    }

    int m0 = w * 64;
    bf16x8 af[4][2];

    // ---- GEMM2: pos = H1 @ dw2 + db2 (C-frags stay in registers) ----
#pragma unroll
    for (int mt = 0; mt < 4; mt++)
#pragma unroll
        for (int k2 = 0; k2 < 2; k2++)
            af[mt][k2] = *(const bf16x8*)&sA[(m0 + mt * 16 + col) * 72 + quad * 8 + k2 * 32];

    f32x4 pos[4][4];
#pragma unroll
    for (int nt = 0; nt < 4; nt++) {
        float bias = db2[nt * 16 + col];
        bf16x8 b0, b1;
        {
            const unsigned short* p0 = &sWd2[(nt * 16 + col) * 68 + quad * 8];
            u16x4 l0 = *(const u16x4*)p0, h0 = *(const u16x4*)(p0 + 4);
            u16x4 l1 = *(const u16x4*)(p0 + 32), h1 = *(const u16x4*)(p0 + 36);
#pragma unroll
            for (int z = 0; z < 4; z++) { b0[z] = (short)l0[z]; b0[z+4] = (short)h0[z]; b1[z] = (short)l1[z]; b1[z+4] = (short)h1[z]; }
        }
#pragma unroll
        for (int mt = 0; mt < 4; mt++) {
            f32x4 acc = {bias, bias, bias, bias};
            acc = __builtin_amdgcn_mfma_f32_16x16x32_bf16(af[mt][0], b0, acc, 0, 0, 0);
            acc = __builtin_amdgcn_mfma_f32_16x16x32_bf16(af[mt][1], b1, acc, 0, 0, 0);
            pos[mt][nt] = acc;
        }
    }

    // ---- tvec = q - k_gathered + pos  ->  bf16 into sA (wave-private rows) ----
#pragma unroll
    for (int mt = 0; mt < 4; mt++) {
        int row = r0 + w * 4 + mt;
        int gx[4];
#pragma unroll
        for (int r = 0; r < 4; r++) gx[r] = sidx[w * 64 + mt * 16 + quad * 4 + r];
#pragma unroll
        for (int nt = 0; nt < 4; nt++) {
            int c = nt * 16 + col;
            float qv = Q[row * 64 + c];
#pragma unroll
            for (int r = 0; r < 4; r++) {
                float tv = qv - Kf[gx[r] * 64 + c] + pos[mt][nt][r];
                sA[(m0 + mt * 16 + quad * 4 + r) * 72 + c] = f2bf(tv);
            }
        }
    }

    // ---- GEMM3: h2 = relu(tvec @ gw1 + gb1) -> bf16 into sA ----
#pragma unroll
    for (int mt = 0; mt < 4; mt++)
#pragma unroll
        for (int k2 = 0; k2 < 2; k2++)
            af[mt][k2] = *(const bf16x8*)&sA[(m0 + mt * 16 + col) * 72 + quad * 8 + k2 * 32];

    f32x4 cc4[4][4];
#pragma unroll
    for (int nt = 0; nt < 4; nt++) {
        float bias = gb1[nt * 16 + col];
        bf16x8 b0, b1;
        {
            const unsigned short* p0 = &sWg1[(nt * 16 + col) * 68 + quad * 8];
            u16x4 l0 = *(const u16x4*)p0, h0 = *(const u16x4*)(p0 + 4);
            u16x4 l1 = *(const u16x4*)(p0 + 32), h1 = *(const u16x4*)(p0 + 36);
#pragma unroll
            for (int z = 0; z < 4; z++) { b0[z] = (short)l0[z]; b0[z+4] = (short)h0[z]; b1[z] = (short)l1[z]; b1[z+4] = (short)h1[z]; }
        }
#pragma unroll
        for (int mt = 0; mt < 4; mt++) {
            f32x4 acc = {bias, bias, bias, bias};
            acc = __builtin_amdgcn_mfma_f32_16x16x32_bf16(af[mt][0], b0, acc, 0, 0, 0);
            acc = __builtin_amdgcn_mfma_f32_16x16x32_bf16(af[mt][1], b1, acc, 0, 0, 0);
            cc4[mt][nt] = acc;
        }
    }
#pragma unroll
    for (int mt = 0; mt < 4; mt++)
#pragma unroll
        for (int nt = 0; nt < 4; nt++)
#pragma unroll
            for (int r = 0; r < 4; r++)
                sA[(m0 + mt * 16 + quad * 4 + r) * 72 + nt * 16 + col] = f2bf(fmaxf(cc4[mt][nt][r], 0.f));

    // ---- GEMM4: attn = h2 @ gw2 (gb2 cancels in softmax) ----
#pragma unroll
    for (int mt = 0; mt < 4; mt++)
#pragma unroll
        for (int k2 = 0; k2 < 2; k2++)
            af[mt][k2] = *(const bf16x8*)&sA[(m0 + mt * 16 + col) * 72 + quad * 8 + k2 * 32];

#pragma unroll
    for (int nt = 0; nt < 4; nt++) {
        bf16x8 b0, b1;
        {
            const unsigned short* p0 = &sWg2[(nt * 16 + col) * 68 + quad * 8];
            u16x4 l0 = *(const u16x4*)p0, h0 = *(const u16x4*)(p0 + 4);
            u16x4 l1 = *(const u16x4*)(p0 + 32), h1 = *(const u16x4*)(p0 + 36);
#pragma unroll
            for (int z = 0; z < 4; z++) { b0[z] = (short)l0[z]; b0[z+4] = (short)h0[z]; b1[z] = (short)l1[z]; b1[z+4] = (short)h1[z]; }
        }
#pragma unroll
        for (int mt = 0; mt < 4; mt++) {
            f32x4 acc = {0.f, 0.f, 0.f, 0.f};
            acc = __builtin_amdgcn_mfma_f32_16x16x32_bf16(af[mt][0], b0, acc, 0, 0, 0);
            acc = __builtin_amdgcn_mfma_f32_16x16x32_bf16(af[mt][1], b1, acc, 0, 0, 0);
            cc4[mt][nt] = acc;
        }
    }

    // ---- softmax over 16 neighbors (= one C-tile's rows) + weighted sum ----
#pragma unroll
    for (int mt = 0; mt < 4; mt++) {
        int row = r0 + w * 4 + mt;
        int gx[4];
#pragma unroll
        for (int r = 0; r < 4; r++) gx[r] = sidx[w * 64 + mt * 16 + quad * 4 + r];
#pragma unroll
        for (int nt = 0; nt < 4; nt++) {
            int c = nt * 16 + col;
            f32x4 a = cc4[mt][nt];
            float mx = fmaxf(fmaxf(a[0], a[1]), fmaxf(a[2], a[3]));
            mx = fmaxf(mx, __shfl_xor(mx, 16, 64));
            mx = fmaxf(mx, __shfl_xor(mx, 32, 64));
            float es = 0.f, ws = 0.f;
#pragma unroll
            for (int r = 0; r < 4; r++) {
                float e = __expf(a[r] - mx);
                float vv = Vf[gx[r] * 64 + c] + pos[mt][nt][r];
                es += e;
                ws = fmaf(e, vv, ws);
            }
            es += __shfl_xor(es, 16, 64); es += __shfl_xor(es, 32, 64);
            ws += __shfl_xor(ws, 16, 64); ws += __shfl_xor(ws, 32, 64);
            if (quad == 0) {
                res[row * 64 + c] = ws / es + feats[row * 64 + c];
            }
        }
    }
}

// ---------------- batchnorm reduce ----------------
__global__ __launch_bounds__(256) void reduce_kernel(const float* __restrict__ res,
                                                     float* __restrict__ accum) {
    __shared__ float sa[256], sq[256];
    int tid = threadIdx.x;
    const float* basep = res + blockIdx.x * 4096;
    float s = 0.f, q = 0.f;
#pragma unroll
    for (int i = 0; i < 16; i++) {
        float v = basep[i * 256 + tid];
        s += v;
        q = fmaf(v, v, q);
    }
    sa[tid] = s; sq[tid] = q;
    __syncthreads();
    if (tid < 64) {
        float ss = sa[tid] + sa[tid + 64] + sa[tid + 128] + sa[tid + 192];
        float qq = sq[tid] + sq[tid + 64] + sq[tid + 128] + sq[tid + 192];
        atomicAdd(&accum[tid], ss);
        atomicAdd(&accum[64 + tid], qq);
    }
}

// ---------------- batchnorm apply + fp32 output ----------------
__global__ __launch_bounds__(256) void norm_kernel(const float* __restrict__ res,
                                                   const float* __restrict__ accum,
                                                   const float* __restrict__ bng,
                                                   const float* __restrict__ bnb,
                                                   float* __restrict__ out) {
    int i = blockIdx.x * 256 + threadIdx.x;
    int c = i & 63;
    float mean = accum[c] * (1.f / 16384.f);
    float var = accum[64 + c] * (1.f / 16384.f) - mean * mean;
    float sc = rsqrtf(var + 1e-5f) * bng[c];
    out[i] = fmaf(res[i] - mean, sc, bnb[c]);
}

extern "C" void kernel_launch(void* const* d_in, const int* in_sizes, int n_in,
                              void* d_out, int out_size, void* d_ws, size_t ws_size,
                              hipStream_t stream) {
    const float* xyz  = (const float*)d_in[0];
    const float* feats = (const float*)d_in[1];
    const float* w_qs = (const float*)d_in[2];
    const float* w_ks = (const float*)d_in[3];
    const float* w_vs = (const float*)d_in[4];
    const float* dw1 = (const float*)d_in[5];
    const float* db1 = (const float*)d_in[6];
    const float* dw2 = (const float*)d_in[7];
    const float* db2 = (const float*)d_in[8];
    const float* gw1 = (const float*)d_in[9];
    const float* gb1 = (const float*)d_in[10];
    const float* gw2 = (const float*)d_in[11];
    const float* bng = (const float*)d_in[13];
    const float* bnb = (const float*)d_in[14];

    char* ws = (char*)d_ws;
    float4* xyz4 = (float4*)ws;                       // 256 KB
    int* knn    = (int*)(ws + 262144);                // 1 MB
    float* Q    = (float*)(ws + 1310720);             // 4 MB
    float* Kf   = (float*)(ws + 5505024);             // 4 MB
    float* Vf   = (float*)(ws + 9699328);             // 4 MB
    float* res  = (float*)(ws + 13893632);            // 4 MB
    float* accum = (float*)(ws + 18087936);           // 512 B

    hipMemsetAsync(accum, 0, 512, stream);
    pack_xyz<<<64, 256, 0, stream>>>(xyz, xyz4);
    knn_kernel<<<16384, 256, 0, stream>>>(xyz4, knn);
    qkv_kernel<<<256, 256, 0, stream>>>(feats, w_qs, w_ks, w_vs, Q, Kf, Vf);
    attn_mfma<<<1024, 256, 0, stream>>>(xyz4, knn, Q, Kf, Vf, feats,
                                        dw1, db1, dw2, db2, gw1, gb1, gw2, res);
    reduce_kernel<<<256, 256, 0, stream>>>(res, accum);
    norm_kernel<<<4096, 256, 0, stream>>>(res, accum, bng, bnb, (float*)d_out);
}